// Round 1
// baseline (290.598 us; speedup 1.0000x reference)
//
#include <hip/hip_runtime.h>
#include <hip/hip_bf16.h>

#define NB 8
#define SS 2048
#define DD 256
#define QT 64
#define STL 64
#define NTILES (SS / STL)
#define SCALE_INV 0.0625f

typedef __attribute__((ext_vector_type(8))) short bf16x8;   // 8 bf16 in 4 VGPRs
typedef __attribute__((ext_vector_type(4))) float f32x4;

#define Q_LD  (DD + 8)    // bf16 elems per row, +16B pad to spread banks
#define C_LD  (DD + 8)
#define CT_LD (STL + 8)
#define P_LD  (STL + 8)

static __device__ __forceinline__ unsigned short f2bf(float f) {
  unsigned int u = __builtin_bit_cast(unsigned int, f);
  u += 0x7FFFu + ((u >> 16) & 1u);   // round-to-nearest-even; inputs are finite
  return (unsigned short)(u >> 16);
}

__global__ __launch_bounds__(256, 1)
void attn_fused(const float* __restrict__ ctx,
                const float* __restrict__ qry,
                const int* __restrict__ lenp,
                float* __restrict__ att_out,
                float* __restrict__ sc_out)
{
  __shared__ unsigned short Qs[QT][Q_LD];    // Q tile bf16
  __shared__ unsigned short Cs[STL][C_LD];   // C tile bf16 [s][d]
  __shared__ unsigned short Ct[DD][CT_LD];   // C tile bf16 transposed [d][s]
  __shared__ unsigned short Ps[QT][P_LD];    // P tile bf16 [q][s]
  __shared__ float partials[4][QT];
  __shared__ float inv_s[QT];

  const int tid = threadIdx.x;
  const int wv  = tid >> 6;
  const int lane = tid & 63;
  const int l15 = lane & 15;
  const int l4  = lane >> 4;

  const int b  = blockIdx.x >> 5;          // 32 q-tiles per batch
  const int q0 = (blockIdx.x & 31) * QT;

  // length: harness doc says int32, reference says int64 — disambiguate.
  // int32 data: values in [1,2048] so odd words can't all be zero.
  int len;
  {
    const int* lp = lenp;
    bool is64 = ((lp[1] | lp[3] | lp[5] | lp[7]) == 0);
    len = is64 ? lp[2 * b] : lp[b];
  }

  const float* ctx_b = ctx + (size_t)b * SS * DD;

  // ---- stage Q tile fp32 -> bf16 ----
  {
    const float* src = qry + ((size_t)b * SS + q0) * DD;
    for (int idx = tid; idx < QT * (DD / 4); idx += 256) {
      int r = idx >> 6, c4 = idx & 63;
      float4 v = *(const float4*)(src + r * DD + c4 * 4);
      ushort4 o;
      o.x = f2bf(v.x); o.y = f2bf(v.y); o.z = f2bf(v.z); o.w = f2bf(v.w);
      *(ushort4*)(&Qs[r][c4 * 4]) = o;
    }
  }

  // =============== phase 1: row sums of exp(QK^T/16) ===============
  float psum[4][4];
  #pragma unroll
  for (int qi = 0; qi < 4; ++qi)
    #pragma unroll
    for (int j = 0; j < 4; ++j) psum[qi][j] = 0.f;

  for (int st = 0; st < NTILES; ++st) {
    __syncthreads();
    {
      const float* src = ctx_b + (size_t)st * STL * DD;
      for (int idx = tid; idx < STL * (DD / 4); idx += 256) {
        int r = idx >> 6, c4 = idx & 63;
        float4 v = *(const float4*)(src + r * DD + c4 * 4);
        ushort4 o;
        o.x = f2bf(v.x); o.y = f2bf(v.y); o.z = f2bf(v.z); o.w = f2bf(v.w);
        *(ushort4*)(&Cs[r][c4 * 4]) = o;
      }
    }
    __syncthreads();

    f32x4 acc[4];
    #pragma unroll
    for (int qi = 0; qi < 4; ++qi) acc[qi] = f32x4{0.f, 0.f, 0.f, 0.f};
    #pragma unroll
    for (int kk = 0; kk < 8; ++kk) {
      bf16x8 bf = *(const bf16x8*)(&Cs[wv * 16 + l15][kk * 32 + l4 * 8]);
      #pragma unroll
      for (int qi = 0; qi < 4; ++qi) {
        bf16x8 af = *(const bf16x8*)(&Qs[qi * 16 + l15][kk * 32 + l4 * 8]);
        acc[qi] = __builtin_amdgcn_mfma_f32_16x16x32_bf16(af, bf, acc[qi], 0, 0, 0);
      }
    }
    int sg = st * STL + wv * 16 + l15;
    bool sval = sg < len;
    #pragma unroll
    for (int qi = 0; qi < 4; ++qi)
      #pragma unroll
      for (int j = 0; j < 4; ++j)
        psum[qi][j] += sval ? __expf(acc[qi][j] * SCALE_INV) : 0.f;
  }

  // reduce partial sums across the 16 lanes of each s-column group
  #pragma unroll
  for (int off = 1; off < 16; off <<= 1)
    #pragma unroll
    for (int qi = 0; qi < 4; ++qi)
      #pragma unroll
      for (int j = 0; j < 4; ++j)
        psum[qi][j] += __shfl_xor(psum[qi][j], off, 64);
  if (l15 == 0) {
    #pragma unroll
    for (int qi = 0; qi < 4; ++qi)
      #pragma unroll
      for (int j = 0; j < 4; ++j)
        partials[wv][qi * 16 + l4 * 4 + j] = psum[qi][j];
  }
  __syncthreads();
  if (tid < QT) {
    float rs = partials[0][tid] + partials[1][tid] + partials[2][tid] + partials[3][tid];
    inv_s[tid] = (q0 + tid < len) ? (1.0f / rs) : 0.f;   // masked q rows -> exact zeros
  }

  // =============== phase 2: normalized scores + PV ===============
  f32x4 accv[4][4];
  #pragma unroll
  for (int qi = 0; qi < 4; ++qi)
    #pragma unroll
    for (int nt = 0; nt < 4; ++nt) accv[qi][nt] = f32x4{0.f, 0.f, 0.f, 0.f};

  for (int st = 0; st < NTILES; ++st) {
    __syncthreads();
    {
      const float* src = ctx_b + (size_t)st * STL * DD;
      for (int idx = tid; idx < STL * (DD / 4); idx += 256) {
        int r = idx >> 6, c4 = idx & 63;
        float4 v = *(const float4*)(src + r * DD + c4 * 4);
        ushort4 o;
        o.x = f2bf(v.x); o.y = f2bf(v.y); o.z = f2bf(v.z); o.w = f2bf(v.w);
        *(ushort4*)(&Cs[r][c4 * 4]) = o;
      }
    }
    __syncthreads();

    // QK^T again
    f32x4 acc[4];
    #pragma unroll
    for (int qi = 0; qi < 4; ++qi) acc[qi] = f32x4{0.f, 0.f, 0.f, 0.f};
    #pragma unroll
    for (int kk = 0; kk < 8; ++kk) {
      bf16x8 bf = *(const bf16x8*)(&Cs[wv * 16 + l15][kk * 32 + l4 * 8]);
      #pragma unroll
      for (int qi = 0; qi < 4; ++qi) {
        bf16x8 af = *(const bf16x8*)(&Qs[qi * 16 + l15][kk * 32 + l4 * 8]);
        acc[qi] = __builtin_amdgcn_mfma_f32_16x16x32_bf16(af, bf, acc[qi], 0, 0, 0);
      }
    }

    // LDS transpose Cs[s][d] -> Ct[d][s] (conflict-light: coalesced row writes)
    #pragma unroll
    for (int i = 0; i < 8; ++i) {
      int d0 = (wv + i * 4) * 8;
      bf16x8 v = *(const bf16x8*)(&Cs[lane][d0]);
      #pragma unroll
      for (int j = 0; j < 8; ++j) Ct[d0 + j][lane] = (unsigned short)v[j];
    }

    // normalized scores: write global + stage bf16 P tile
    {
      int sl = wv * 16 + l15;
      int sg = st * STL + sl;
      bool sval = sg < len;
      #pragma unroll
      for (int qi = 0; qi < 4; ++qi)
        #pragma unroll
        for (int j = 0; j < 4; ++j) {
          int row = qi * 16 + l4 * 4 + j;
          float p = sval ? __expf(acc[qi][j] * SCALE_INV) * inv_s[row] : 0.f;
          sc_out[((size_t)(b * SS + q0 + row)) * SS + sg] = p;
          Ps[row][sl] = f2bf(p);
        }
    }
    __syncthreads();

    // PV: attended += P @ C   (wave owns d columns [wv*64, wv*64+64))
    #pragma unroll
    for (int kk = 0; kk < 2; ++kk) {
      bf16x8 pa[4], cb[4];
      #pragma unroll
      for (int qi = 0; qi < 4; ++qi)
        pa[qi] = *(const bf16x8*)(&Ps[qi * 16 + l15][kk * 32 + l4 * 8]);
      #pragma unroll
      for (int nt = 0; nt < 4; ++nt)
        cb[nt] = *(const bf16x8*)(&Ct[wv * 64 + nt * 16 + l15][kk * 32 + l4 * 8]);
      #pragma unroll
      for (int qi = 0; qi < 4; ++qi)
        #pragma unroll
        for (int nt = 0; nt < 4; ++nt)
          accv[qi][nt] = __builtin_amdgcn_mfma_f32_16x16x32_bf16(pa[qi], cb[nt], accv[qi][nt], 0, 0, 0);
    }
  }

  // write attended
  #pragma unroll
  for (int qi = 0; qi < 4; ++qi)
    #pragma unroll
    for (int nt = 0; nt < 4; ++nt)
      #pragma unroll
      for (int j = 0; j < 4; ++j) {
        int row = qi * 16 + l4 * 4 + j;
        int col = wv * 64 + nt * 16 + l15;
        att_out[((size_t)(b * SS + q0 + row)) * DD + col] = accv[qi][nt][j];
      }
}

extern "C" void kernel_launch(void* const* d_in, const int* in_sizes, int n_in,
                              void* d_out, int out_size, void* d_ws, size_t ws_size,
                              hipStream_t stream) {
  const float* ctx = (const float*)d_in[0];
  const float* qry = (const float*)d_in[1];
  const int* len   = (const int*)d_in[2];
  float* att = (float*)d_out;
  float* sc  = att + (size_t)NB * SS * DD;
  dim3 grid(NB * (SS / QT));
  attn_fused<<<grid, dim3(256), 0, stream>>>(ctx, qry, len, att, sc);
}

// Round 2
// 92.606 us; speedup vs baseline: 3.1380x; 3.1380x over previous
//
#include <hip/hip_runtime.h>
#include <hip/hip_bf16.h>

#define NB 8
#define SS 2048
#define DD 256
#define SCALE_INV 0.0625f

typedef __attribute__((ext_vector_type(8))) short bf16x8;
typedef __attribute__((ext_vector_type(4))) float f32x4;

#define MFMA __builtin_amdgcn_mfma_f32_16x16x32_bf16

static __device__ __forceinline__ unsigned short f2bf(float f) {
  unsigned int u = __builtin_bit_cast(unsigned int, f);
  u += 0x7FFFu + ((u >> 16) & 1u);
  return (unsigned short)(u >> 16);
}

static __device__ __forceinline__ void gll16(const void* g, void* l) {
  __builtin_amdgcn_global_load_lds(
      (const __attribute__((address_space(1))) unsigned int*)g,
      (__attribute__((address_space(3))) unsigned int*)l, 16, 0, 0);
}

// ---------------- kernel 0: f32 -> bf16 + transposed bf16 copy ----------------
__global__ __launch_bounds__(256)
void preconv(const float* __restrict__ ctx,
             unsigned short* __restrict__ cbf,   // [b][s][d]
             unsigned short* __restrict__ cT)    // [b][d][s]
{
  __shared__ unsigned short T[64][68];
  const int tid = threadIdx.x;
  const int s0 = blockIdx.x * 64, d0 = blockIdx.y * 64, b = blockIdx.z;
  const int r = tid >> 4, c4 = tid & 15;

  #pragma unroll
  for (int i = 0; i < 4; ++i) {
    int row = i * 16 + r;
    size_t gi = ((size_t)(b * SS + s0 + row)) * DD + d0 + c4 * 4;
    float4 v = *(const float4*)(ctx + gi);
    ushort4 o;
    o.x = f2bf(v.x); o.y = f2bf(v.y); o.z = f2bf(v.z); o.w = f2bf(v.w);
    *(ushort4*)(cbf + gi) = o;
    T[c4 * 4 + 0][row] = o.x;
    T[c4 * 4 + 1][row] = o.y;
    T[c4 * 4 + 2][row] = o.z;
    T[c4 * 4 + 3][row] = o.w;
  }
  __syncthreads();
  const int rr = tid >> 2, cc = tid & 3;
  #pragma unroll
  for (int j = 0; j < 4; ++j) {
    size_t go = ((size_t)(b * DD + d0 + rr)) * SS + s0 + cc * 16 + j * 4;
    *(ushort4*)(cT + go) = *(const ushort4*)&T[rr][cc * 16 + j * 4];
  }
}

// ---------------- main fused kernel (fast path) ----------------
// QT=32 rows/block, STL=64 keys/tile, 256 threads (4 waves), grid 512.
#define CS_OFF   0
#define CT_OFF   32768
#define PS_OFF   65536
#define PART_OFF 70144
#define INVS_OFF 70656
#define SMEM_BYTES 70784

__global__ __launch_bounds__(256, 2)
void attn_fast(const unsigned short* __restrict__ cbf,
               const unsigned short* __restrict__ cT,
               const float* __restrict__ qry,
               const int* __restrict__ lenp,
               float* __restrict__ att,
               float* __restrict__ sc)
{
  __shared__ __align__(16) unsigned char smem[SMEM_BYTES];

  const int tid = threadIdx.x;
  const int wv = tid >> 6;
  const int lane = tid & 63;
  const int l15 = lane & 15;
  const int l4 = lane >> 4;

  const int wg = blockIdx.x;
  const int b = wg >> 6;
  const int q0 = (wg & 63) * 32;
  const int bq = b * SS + q0;

  int len;
  {
    const int* lp = lenp;
    bool is64 = ((lp[1] | lp[3] | lp[5] | lp[7]) == 0);
    len = is64 ? lp[2 * b] : lp[b];
  }
  const int nt_act = (len + 63) >> 6;   // 1..32

  const char* cbf_b = (const char*)cbf + (size_t)b * SS * DD * 2;
  const char* cT_b  = (const char*)cT  + (size_t)b * SS * DD * 2;

  auto stage_cs = [&](unsigned char* buf, int st) {
    const char* gb = cbf_b + ((size_t)st << 15);
    #pragma unroll
    for (int r = 0; r < 8; ++r) {
      int chunk = r * 256 + tid;
      int s = chunk >> 5, c = chunk & 31;
      gll16(gb + ((size_t)s << 9) + ((c ^ (s & 7)) << 4), buf + chunk * 16);
    }
  };
  auto stage_ct = [&](int st) {
    const char* gb = cT_b + st * 128;
    unsigned char* buf = smem + CT_OFF;
    #pragma unroll
    for (int r = 0; r < 8; ++r) {
      int chunk = r * 256 + tid;
      int d = chunk >> 3, c = chunk & 7;
      gll16(gb + (size_t)d * 4096 + ((c ^ (d & 7)) << 4), buf + chunk * 16);
    }
  };

  // ---- Q fragments -> registers (A operand; m = l15 row, k = l4*8+j) ----
  bf16x8 qf[2][8];
  {
    const float* qb = qry + ((size_t)b * SS + q0) * DD;
    #pragma unroll
    for (int qi = 0; qi < 2; ++qi)
      #pragma unroll
      for (int kk = 0; kk < 8; ++kk) {
        const float4* qp = (const float4*)(qb + (size_t)(qi * 16 + l15) * DD + kk * 32 + l4 * 8);
        float4 x = qp[0], y = qp[1];
        bf16x8 f;
        f[0] = (short)f2bf(x.x); f[1] = (short)f2bf(x.y);
        f[2] = (short)f2bf(x.z); f[3] = (short)f2bf(x.w);
        f[4] = (short)f2bf(y.x); f[5] = (short)f2bf(y.y);
        f[6] = (short)f2bf(y.z); f[7] = (short)f2bf(y.w);
        qf[qi][kk] = f;
      }
  }

  const int sl = wv * 16 + l15;   // this wave's key column within a tile

  // =============== phase 1: row sums of exp(QK^T/16) ===============
  float ps0[4] = {0.f, 0.f, 0.f, 0.f};
  float ps1[4] = {0.f, 0.f, 0.f, 0.f};

  unsigned char* buf0 = smem + CS_OFF;
  unsigned char* buf1 = smem + CT_OFF;   // Ct region doubles as phase-1 buffer
  stage_cs(buf0, 0);

  for (int t = 0; t < nt_act; ++t) {
    __syncthreads();                       // tile t staged & visible
    unsigned char* cur = (t & 1) ? buf1 : buf0;
    if (t + 1 < nt_act) stage_cs((t & 1) ? buf0 : buf1, t + 1);

    f32x4 a0 = {0.f, 0.f, 0.f, 0.f}, a1 = {0.f, 0.f, 0.f, 0.f};
    const unsigned char* rowp = cur + sl * 512;
    #pragma unroll
    for (int kk = 0; kk < 8; ++kk) {
      bf16x8 bfr = *(const bf16x8*)(rowp + (((kk * 4 + l4) ^ (sl & 7)) << 4));
      a0 = MFMA(qf[0][kk], bfr, a0, 0, 0, 0);
      a1 = MFMA(qf[1][kk], bfr, a1, 0, 0, 0);
    }
    bool sval = (t * 64 + sl) < len;
    #pragma unroll
    for (int j = 0; j < 4; ++j) {
      ps0[j] += sval ? __expf(a0[j] * SCALE_INV) : 0.f;
      ps1[j] += sval ? __expf(a1[j] * SCALE_INV) : 0.f;
    }
  }

  // reduce over the 16 key-lanes, then over the 4 waves
  #pragma unroll
  for (int off = 1; off < 16; off <<= 1)
    #pragma unroll
    for (int j = 0; j < 4; ++j) {
      ps0[j] += __shfl_xor(ps0[j], off, 64);
      ps1[j] += __shfl_xor(ps1[j], off, 64);
    }
  float* part = (float*)(smem + PART_OFF);
  if (l15 == 0) {
    #pragma unroll
    for (int j = 0; j < 4; ++j) {
      part[wv * 32 + l4 * 4 + j] = ps0[j];
      part[wv * 32 + 16 + l4 * 4 + j] = ps1[j];
    }
  }
  __syncthreads();                          // partials visible, phase-1 LDS reads done
  stage_cs(smem + CS_OFF, 0);               // prefetch phase-2 tile 0
  stage_ct(0);
  float* invs = (float*)(smem + INVS_OFF);
  if (tid < 32) {
    float rs = part[tid] + part[32 + tid] + part[64 + tid] + part[96 + tid];
    invs[tid] = (q0 + tid < len) ? (1.0f / rs) : 0.f;
  }
  __syncthreads();                          // invs + staged tile 0 visible

  // =============== phase 2: scores + PV ===============
  f32x4 av0[4] = {{0.f,0.f,0.f,0.f},{0.f,0.f,0.f,0.f},{0.f,0.f,0.f,0.f},{0.f,0.f,0.f,0.f}};
  f32x4 av1[4] = {{0.f,0.f,0.f,0.f},{0.f,0.f,0.f,0.f},{0.f,0.f,0.f,0.f},{0.f,0.f,0.f,0.f}};
  unsigned short* Ps = (unsigned short*)(smem + PS_OFF);

  for (int t = 0; t < nt_act; ++t) {
    // QK^T on staged tile
    f32x4 a0 = {0.f, 0.f, 0.f, 0.f}, a1 = {0.f, 0.f, 0.f, 0.f};
    const unsigned char* rowp = smem + CS_OFF + sl * 512;
    #pragma unroll
    for (int kk = 0; kk < 8; ++kk) {
      bf16x8 bfr = *(const bf16x8*)(rowp + (((kk * 4 + l4) ^ (sl & 7)) << 4));
      a0 = MFMA(qf[0][kk], bfr, a0, 0, 0, 0);
      a1 = MFMA(qf[1][kk], bfr, a1, 0, 0, 0);
    }
    int sg = t * 64 + sl;
    bool sval = sg < len;
    #pragma unroll
    for (int qi = 0; qi < 2; ++qi) {
      #pragma unroll
      for (int j = 0; j < 4; ++j) {
        int row = qi * 16 + l4 * 4 + j;
        float v = qi ? a1[j] : a0[j];
        float p = sval ? __expf(v * SCALE_INV) * invs[row] : 0.f;
        sc[(size_t)(bq + row) * SS + sg] = p;
        Ps[row * 72 + sl] = f2bf(p);
      }
    }
    __syncthreads();                        // Ps visible; Cs reads complete

    // preload PV fragments to registers
    bf16x8 pa0[2], pa1[2], cb[4][2];
    #pragma unroll
    for (int k2 = 0; k2 < 2; ++k2) {
      pa0[k2] = *(const bf16x8*)((const unsigned char*)Ps + (l15) * 144 + k2 * 64 + l4 * 16);
      pa1[k2] = *(const bf16x8*)((const unsigned char*)Ps + (16 + l15) * 144 + k2 * 64 + l4 * 16);
      #pragma unroll
      for (int nt = 0; nt < 4; ++nt) {
        int d = wv * 64 + nt * 16 + l15;
        cb[nt][k2] = *(const bf16x8*)(smem + CT_OFF + d * 128 + (((k2 * 4 + l4) ^ (d & 7)) << 4));
      }
    }
    __syncthreads();                        // all LDS reads complete -> safe to overwrite

    if (t + 1 < nt_act) { stage_cs(smem + CS_OFF, t + 1); stage_ct(t + 1); }

    #pragma unroll
    for (int k2 = 0; k2 < 2; ++k2)
      #pragma unroll
      for (int nt = 0; nt < 4; ++nt) {
        av0[nt] = MFMA(pa0[k2], cb[nt][k2], av0[nt], 0, 0, 0);
        av1[nt] = MFMA(pa1[k2], cb[nt][k2], av1[nt], 0, 0, 0);
      }
    __syncthreads();                        // staged tile t+1 visible at loop top
  }

  // zero-fill score columns >= nt_act*64
  {
    int s_start = nt_act * 64;
    int rem4 = (SS - s_start) >> 2;
    if (rem4 > 0) {
      float4 z = {0.f, 0.f, 0.f, 0.f};
      for (int row = 0; row < 32; ++row)
        for (int c = tid; c < rem4; c += 256)
          *(float4*)(sc + (size_t)(bq + row) * SS + s_start + c * 4) = z;
    }
  }

  // write attended
  #pragma unroll
  for (int nt = 0; nt < 4; ++nt)
    #pragma unroll
    for (int j = 0; j < 4; ++j) {
      int col = wv * 64 + nt * 16 + l15;
      att[(size_t)(bq + l4 * 4 + j) * DD + col] = av0[nt][j];
      att[(size_t)(bq + 16 + l4 * 4 + j) * DD + col] = av1[nt][j];
    }
}

// ---------------- fallback (round-1 kernel, used only if ws too small) ----------------
#define QT 64
#define STL 64
#define NTILES (SS / STL)
#define Q_LD  (DD + 8)
#define C_LD  (DD + 8)
#define CT_LD (STL + 8)
#define P_LD  (STL + 8)

__global__ __launch_bounds__(256, 1)
void attn_fb(const float* __restrict__ ctx,
             const float* __restrict__ qry,
             const int* __restrict__ lenp,
             float* __restrict__ att_out,
             float* __restrict__ sc_out)
{
  __shared__ unsigned short Qs[QT][Q_LD];
  __shared__ unsigned short Cs[STL][C_LD];
  __shared__ unsigned short Ct[DD][CT_LD];
  __shared__ unsigned short Ps[QT][P_LD];
  __shared__ float partials[4][QT];
  __shared__ float inv_s[QT];

  const int tid = threadIdx.x;
  const int wv = tid >> 6;
  const int lane = tid & 63;
  const int l15 = lane & 15;
  const int l4 = lane >> 4;
  const int b = blockIdx.x >> 5;
  const int q0 = (blockIdx.x & 31) * QT;

  int len;
  {
    const int* lp = lenp;
    bool is64 = ((lp[1] | lp[3] | lp[5] | lp[7]) == 0);
    len = is64 ? lp[2 * b] : lp[b];
  }
  const float* ctx_b = ctx + (size_t)b * SS * DD;

  {
    const float* src = qry + ((size_t)b * SS + q0) * DD;
    for (int idx = tid; idx < QT * (DD / 4); idx += 256) {
      int r = idx >> 6, c4 = idx & 63;
      float4 v = *(const float4*)(src + r * DD + c4 * 4);
      ushort4 o;
      o.x = f2bf(v.x); o.y = f2bf(v.y); o.z = f2bf(v.z); o.w = f2bf(v.w);
      *(ushort4*)(&Qs[r][c4 * 4]) = o;
    }
  }

  float psum[4][4];
  #pragma unroll
  for (int qi = 0; qi < 4; ++qi)
    #pragma unroll
    for (int j = 0; j < 4; ++j) psum[qi][j] = 0.f;

  for (int st = 0; st < NTILES; ++st) {
    __syncthreads();
    {
      const float* src = ctx_b + (size_t)st * STL * DD;
      for (int idx = tid; idx < STL * (DD / 4); idx += 256) {
        int r = idx >> 6, c4 = idx & 63;
        float4 v = *(const float4*)(src + r * DD + c4 * 4);
        ushort4 o;
        o.x = f2bf(v.x); o.y = f2bf(v.y); o.z = f2bf(v.z); o.w = f2bf(v.w);
        *(ushort4*)(&Cs[r][c4 * 4]) = o;
      }
    }
    __syncthreads();
    f32x4 acc[4];
    #pragma unroll
    for (int qi = 0; qi < 4; ++qi) acc[qi] = f32x4{0.f, 0.f, 0.f, 0.f};
    #pragma unroll
    for (int kk = 0; kk < 8; ++kk) {
      bf16x8 bf = *(const bf16x8*)(&Cs[wv * 16 + l15][kk * 32 + l4 * 8]);
      #pragma unroll
      for (int qi = 0; qi < 4; ++qi) {
        bf16x8 af = *(const bf16x8*)(&Qs[qi * 16 + l15][kk * 32 + l4 * 8]);
        acc[qi] = MFMA(af, bf, acc[qi], 0, 0, 0);
      }
    }
    int sg = st * STL + wv * 16 + l15;
    bool sval = sg < len;
    #pragma unroll
    for (int qi = 0; qi < 4; ++qi)
      #pragma unroll
      for (int j = 0; j < 4; ++j)
        psum[qi][j] += sval ? __expf(acc[qi][j] * SCALE_INV) : 0.f;
  }

  #pragma unroll
  for (int off = 1; off < 16; off <<= 1)
    #pragma unroll
    for (int qi = 0; qi < 4; ++qi)
      #pragma unroll
      for (int j = 0; j < 4; ++j)
        psum[qi][j] += __shfl_xor(psum[qi][j], off, 64);
  if (l15 == 0) {
    #pragma unroll
    for (int qi = 0; qi < 4; ++qi)
      #pragma unroll
      for (int j = 0; j < 4; ++j)
        partials[wv][qi * 16 + l4 * 4 + j] = psum[qi][j];
  }
  __syncthreads();
  if (tid < QT) {
    float rs = partials[0][tid] + partials[1][tid] + partials[2][tid] + partials[3][tid];
    inv_s[tid] = (q0 + tid < len) ? (1.0f / rs) : 0.f;
  }

  f32x4 accv[4][4];
  #pragma unroll
  for (int qi = 0; qi < 4; ++qi)
    #pragma unroll
    for (int nt = 0; nt < 4; ++nt) accv[qi][nt] = f32x4{0.f, 0.f, 0.f, 0.f};

  for (int st = 0; st < NTILES; ++st) {
    __syncthreads();
    {
      const float* src = ctx_b + (size_t)st * STL * DD;
      for (int idx = tid; idx < STL * (DD / 4); idx += 256) {
        int r = idx >> 6, c4 = idx & 63;
        float4 v = *(const float4*)(src + r * DD + c4 * 4);
        ushort4 o;
        o.x = f2bf(v.x); o.y = f2bf(v.y); o.z = f2bf(v.z); o.w = f2bf(v.w);
        *(ushort4*)(&Cs[r][c4 * 4]) = o;
      }
    }
    __syncthreads();

    f32x4 acc[4];
    #pragma unroll
    for (int qi = 0; qi < 4; ++qi) acc[qi] = f32x4{0.f, 0.f, 0.f, 0.f};
    #pragma unroll
    for (int kk = 0; kk < 8; ++kk) {
      bf16x8 bf = *(const bf16x8*)(&Cs[wv * 16 + l15][kk * 32 + l4 * 8]);
      #pragma unroll
      for (int qi = 0; qi < 4; ++qi) {
        bf16x8 af = *(const bf16x8*)(&Qs[qi * 16 + l15][kk * 32 + l4 * 8]);
        acc[qi] = MFMA(af, bf, acc[qi], 0, 0, 0);
      }
    }

    #pragma unroll
    for (int i = 0; i < 8; ++i) {
      int d0 = (wv + i * 4) * 8;
      bf16x8 v = *(const bf16x8*)(&Cs[lane][d0]);
      #pragma unroll
      for (int j = 0; j < 8; ++j) Ct[d0 + j][lane] = (unsigned short)v[j];
    }

    {
      int sl = wv * 16 + l15;
      int sg = st * STL + sl;
      bool sval = sg < len;
      #pragma unroll
      for (int qi = 0; qi < 4; ++qi)
        #pragma unroll
        for (int j = 0; j < 4; ++j) {
          int row = qi * 16 + l4 * 4 + j;
          float p = sval ? __expf(acc[qi][j] * SCALE_INV) * inv_s[row] : 0.f;
          sc_out[((size_t)(b * SS + q0 + row)) * SS + sg] = p;
          Ps[row][sl] = f2bf(p);
        }
    }
    __syncthreads();

    #pragma unroll
    for (int kk = 0; kk < 2; ++kk) {
      bf16x8 pa[4], cbv[4];
      #pragma unroll
      for (int qi = 0; qi < 4; ++qi)
        pa[qi] = *(const bf16x8*)(&Ps[qi * 16 + l15][kk * 32 + l4 * 8]);
      #pragma unroll
      for (int nt = 0; nt < 4; ++nt)
        cbv[nt] = *(const bf16x8*)(&Ct[wv * 64 + nt * 16 + l15][kk * 32 + l4 * 8]);
      #pragma unroll
      for (int qi = 0; qi < 4; ++qi)
        #pragma unroll
        for (int nt = 0; nt < 4; ++nt)
          accv[qi][nt] = MFMA(pa[qi], cbv[nt], accv[qi][nt], 0, 0, 0);
    }
  }

  #pragma unroll
  for (int qi = 0; qi < 4; ++qi)
    #pragma unroll
    for (int nt = 0; nt < 4; ++nt)
      #pragma unroll
      for (int j = 0; j < 4; ++j) {
        int row = qi * 16 + l4 * 4 + j;
        int col = wv * 64 + nt * 16 + l15;
        att_out[((size_t)(b * SS + q0 + row)) * DD + col] = accv[qi][nt][j];
      }
}

extern "C" void kernel_launch(void* const* d_in, const int* in_sizes, int n_in,
                              void* d_out, int out_size, void* d_ws, size_t ws_size,
                              hipStream_t stream) {
  const float* ctx = (const float*)d_in[0];
  const float* qry = (const float*)d_in[1];
  const int* len = (const int*)d_in[2];
  float* att = (float*)d_out;
  float* sc = att + (size_t)NB * SS * DD;

  size_t need = (size_t)NB * SS * DD * 2 * 2;   // bf16 ctx + bf16 ctx^T
  if (ws_size >= need) {
    unsigned short* cbf = (unsigned short*)d_ws;
    unsigned short* cT = cbf + (size_t)NB * SS * DD;
    preconv<<<dim3(SS / 64, DD / 64, NB), dim3(256), 0, stream>>>(ctx, cbf, cT);
    attn_fast<<<dim3(NB * (SS / 32)), dim3(256), 0, stream>>>(cbf, cT, qry, len, att, sc);
  } else {
    attn_fb<<<dim3(NB * (SS / 64)), dim3(256), 0, stream>>>(ctx, qry, len, att, sc);
  }
}